// Round 4
// baseline (7119.447 us; speedup 1.0000x reference)
//
#include <hip/hip_runtime.h>
#include <stdint.h>
#include <stddef.h>

// Row-parallel linear: C[M][N] = A[M][K] * W[N][K]^T + bias
// M = SEQ*BATCH = 8192, N = D_MODEL = 4096, K = D_FF = 16384
#define M_DIM 8192
#define N_DIM 4096
#define K_DIM 16384

#define BM 256
#define BN 256
#define BK 64
#define NTHR 512                  // 8 waves: 2 (M) x 4 (N)
#define K_TILES (K_DIM / BK)      // 256

typedef __attribute__((ext_vector_type(8))) short bf16x8;   // 8 bf16 = 4 VGPRs
typedef __attribute__((ext_vector_type(4))) float f32x4;    // MFMA C/D

#define AS1 __attribute__((address_space(1)))
#define AS3 __attribute__((address_space(3)))

__device__ __forceinline__ unsigned short f2bf(float f) {
  union { float f; unsigned u; } x; x.f = f;
  unsigned r = x.u + 0x7fffu + ((x.u >> 16) & 1u);
  return (unsigned short)(r >> 16);
}

// ---------------- pass 1: fp32 -> bf16 conversion (memory-bound) --------------
__global__ void cvt_f32_bf16(const float* __restrict__ in,
                             unsigned short* __restrict__ out, long n4) {
  long idx = (long)blockIdx.x * blockDim.x + threadIdx.x;
  long stride = (long)gridDim.x * blockDim.x;
  const float4* in4 = (const float4*)in;
  ushort4* out4 = (ushort4*)out;
  for (long i = idx; i < n4; i += stride) {
    float4 v = in4[i];
    ushort4 o;
    o.x = f2bf(v.x); o.y = f2bf(v.y); o.z = f2bf(v.z); o.w = f2bf(v.w);
    out4[i] = o;
  }
}

// ---------------- pass 2: 256x256 bf16 MFMA GEMM, SINGLE-buffer in-place ------
// 64 KiB LDS (single buffer) -> 2 blocks/CU (4 waves/SIMD): independent barrier
// groups hide each other's waits. In-place staging of tile t+1 into slots freed
// phase-by-phase during iter t (slot's last ds_read drains before the barrier
// preceding the staging issue -> no WAR hazard; RAW gated by counted vmcnt +
// iter-end barrier).
//   ph1: read A0,B0(t) [12 ds]; wait vmcnt(2)  -> B1(t) resident for ph2
//   ph2: read B1(t) [4 ds]; stage A0,B0(t+1); wait vmcnt(4) -> A1(t) for ph3
//   ph3: read A1(t) [8 ds]; stage B1(t+1); no wait
//   ph4: (reuse bf n0-1) stage A1(t+1); wait vmcnt(4) -> A0,B0(t+1) for next ph1
#define BAR()   __builtin_amdgcn_s_barrier()
#define SCHED0() __builtin_amdgcn_sched_barrier(0)
#define WAIT_LGKM0() do { asm volatile("s_waitcnt lgkmcnt(0)" ::: "memory"); \
                          __builtin_amdgcn_sched_barrier(0); } while (0)
#define VMCNT(N) asm volatile("s_waitcnt vmcnt(" #N ")" ::: "memory")

#define MFMA_QUAD(MQ, NP)                                                      \
  do {                                                                         \
    __builtin_amdgcn_s_setprio(1);                                             \
    _Pragma("unroll") for (int mi = 0; mi < 4; ++mi)                           \
      _Pragma("unroll") for (int nn = 0; nn < 2; ++nn)                         \
        _Pragma("unroll") for (int ks = 0; ks < 2; ++ks)                       \
          acc[(MQ)*4 + mi][(NP)*2 + nn] =                                      \
              __builtin_amdgcn_mfma_f32_16x16x32_bf16(                         \
                  af[mi][ks], bf[(NP)*2 + nn][ks],                             \
                  acc[(MQ)*4 + mi][(NP)*2 + nn], 0, 0, 0);                     \
    __builtin_amdgcn_s_setprio(0);                                             \
  } while (0)

__global__ __launch_bounds__(NTHR, 4)
void gemm256(const unsigned short* __restrict__ A,
             const unsigned short* __restrict__ W,
             const float* __restrict__ bias, float* __restrict__ C) {
  __shared__ unsigned short smA[BM * BK];   // 32 KiB
  __shared__ unsigned short smB[BN * BK];   // 32 KiB

  const int tid  = threadIdx.x;
  const int wave = tid >> 6;
  const int lane = tid & 63;
  const int wr = wave >> 2;          // 0..1  (M waves, 128 rows each)
  const int wc = wave & 3;           // 0..3  (N waves, 64 cols each)
  const int g  = lane >> 4;          // frag k-group
  const int xr = (lane & 7) << 4;    // read-side swizzle term

  int csw[2];
  csw[0] = (g * 16) ^ xr;
  csw[1] = (64 + g * 16) ^ xr;

  // XCD-aware bijective swizzle; nwg = 512 (divisible by 8)
  const int nbn = N_DIM / BN;                  // 16
  const int nwg = (M_DIM / BM) * nbn;          // 512
  const int bid = blockIdx.x;
  const int swz = (bid & 7) * (nwg >> 3) + (bid >> 3);
  const int bm = swz / nbn, bn = swz % nbn;
  const int bmBase = bm * BM, bnBase = bn * BN;

  // per-lane pre-swizzled global source offset (elements)
  const size_t laneOff = (size_t)(lane >> 3) * K_DIM +
                         (size_t)(((lane & 7) ^ ((lane >> 3) & 7)) * 8);

  const unsigned short* aSrc =
      A + (size_t)(bmBase + wr * 128 + wc * 16) * K_DIM + laneOff;
  const unsigned short* bSrc =
      W + (size_t)(bnBase + wc * 64 + wr * 16) * K_DIM + laneOff;

  f32x4 acc[8][4];
  const f32x4 z = {0.f, 0.f, 0.f, 0.f};
#pragma unroll
  for (int m = 0; m < 8; ++m)
#pragma unroll
    for (int n = 0; n < 4; ++n) acc[m][n] = z;

  bf16x8 af[4][2];   // current m-quad fragments
  bf16x8 bf[4][2];   // all 4 n fragments

  auto stageA = [&](int mq, size_t kOff) {
#pragma unroll
    for (int j = 0; j < 2; ++j) {
      const unsigned short* src = aSrc + (size_t)(mq * 64 + j * 8) * K_DIM + kOff;
      unsigned short* dst = &smA[(wr * 128 + mq * 64 + wc * 16 + j * 8) * BK];
      __builtin_amdgcn_global_load_lds((AS1 void*)src, (AS3 void*)dst, 16, 0, 0);
    }
  };
  auto stageB = [&](int h, size_t kOff) {
#pragma unroll
    for (int j = 0; j < 2; ++j) {
      const unsigned short* src = bSrc + (size_t)(h * 32 + j * 8) * K_DIM + kOff;
      unsigned short* dst = &smB[(wc * 64 + h * 32 + wr * 16 + j * 8) * BK];
      __builtin_amdgcn_global_load_lds((AS1 void*)src, (AS3 void*)dst, 16, 0, 0);
    }
  };

  const char* aRd = (const char*)&smA[0] + (wr * 128 + (lane & 15)) * 128;
  const char* bRd = (const char*)&smB[0] + (wc * 64 + (lane & 15)) * 128;

  auto readA = [&](int mq) {
#pragma unroll
    for (int mi = 0; mi < 4; ++mi)
#pragma unroll
      for (int ks = 0; ks < 2; ++ks)
        af[mi][ks] = *(const bf16x8*)(aRd + (mq * 64 + mi * 16) * 128 + csw[ks]);
  };
  auto readB = [&](int np) {
#pragma unroll
    for (int nn = 0; nn < 2; ++nn)
#pragma unroll
      for (int ks = 0; ks < 2; ++ks)
        bf[np * 2 + nn][ks] =
            *(const bf16x8*)(bRd + (np * 32 + nn * 16) * 128 + csw[ks]);
  };

  // ---- prologue: stage tile 0 in consumption order A0,B0,B1,A1 ----
  stageA(0, 0); stageB(0, 0); stageB(1, 0); stageA(1, 0);
  VMCNT(4);                        // A0,B0 resident; B1,A1 in flight (out=4)
  BAR(); SCHED0();

  size_t kOff = BK;                // tile t+1
  for (int t = 0; t < K_TILES - 1; ++t) {
    // phase 1: frags (m0-3, n0-1); wait B1(t) for ph2
    readA(0); readB(0);                            // 12 ds_reads
    VMCNT(2);
    asm volatile("s_waitcnt lgkmcnt(8)" ::: "memory");
    BAR(); WAIT_LGKM0();
    MFMA_QUAD(0, 0);
    BAR(); SCHED0();

    // phase 2: frags n2-3; stage A0,B0(t+1) into freed slots; wait A1(t)
    readB(1);                                      // 4 ds_reads
    stageA(0, kOff); stageB(0, kOff);              // 4 loads
    VMCNT(4);
    BAR(); WAIT_LGKM0();
    MFMA_QUAD(0, 1);
    BAR(); SCHED0();

    // phase 3: frags m4-7; stage B1(t+1); no wait
    readA(1);                                      // 8 ds_reads
    stageB(1, kOff);                               // 2 loads
    BAR(); WAIT_LGKM0();
    MFMA_QUAD(1, 1);
    BAR(); SCHED0();

    // phase 4: reuse bf n0-1; stage A1(t+1); wait A0,B0(t+1) for next ph1
    stageA(1, kOff);                               // 2 loads
    VMCNT(4);
    BAR(); SCHED0();
    MFMA_QUAD(1, 0);
    BAR(); SCHED0();

    kOff += BK;
  }

  // ---- final tile: no staging; drain 2 -> 0 ----
  {
    readA(0); readB(0);
    VMCNT(2);
    BAR(); WAIT_LGKM0();
    MFMA_QUAD(0, 0);
    BAR(); SCHED0();

    readB(1);
    VMCNT(0);
    BAR(); WAIT_LGKM0();
    MFMA_QUAD(0, 1);
    BAR(); SCHED0();

    readA(1);
    BAR(); WAIT_LGKM0();
    MFMA_QUAD(1, 1);
    BAR(); SCHED0();

    MFMA_QUAD(1, 0);
  }

  // ---- epilogue: C = acc + bias. C/D layout: col=lane&15, row=(lane>>4)*4+j
  const int crow0 = bmBase + wr * 128 + ((lane >> 4) << 2);
  const int ccol0 = bnBase + wc * 64 + (lane & 15);
#pragma unroll
  for (int n = 0; n < 4; ++n) {
    const float bv = bias[ccol0 + n * 16];
#pragma unroll
    for (int mi = 0; mi < 8; ++mi) {
      const size_t base = (size_t)(crow0 + mi * 16) * N_DIM + (ccol0 + n * 16);
#pragma unroll
      for (int j = 0; j < 4; ++j)
        C[base + (size_t)j * N_DIM] = acc[mi][n][j] + bv;
    }
  }
}

// ---------------- fallback: fused-cvt 128x128 GEMM (ws too small) -------------
__global__ __launch_bounds__(256)
void gemm_fallback(const float* __restrict__ Af, const float* __restrict__ Wf,
                   const float* __restrict__ bias, float* __restrict__ C) {
  __shared__ __align__(16) unsigned short sA[128 * 64];
  __shared__ __align__(16) unsigned short sB[128 * 64];
  const int tid = threadIdx.x, wave = tid >> 6, lane = tid & 63;
  const int wr = wave >> 1, wc = wave & 1;
  const int nbn = N_DIM / 128, nwg = (M_DIM / 128) * nbn;
  const int swz = (blockIdx.x & 7) * (nwg >> 3) + (blockIdx.x >> 3);
  const int bm = swz / nbn, bn = swz % nbn;
  f32x4 acc[4][4];
  const f32x4 z = {0.f, 0.f, 0.f, 0.f};
#pragma unroll
  for (int m = 0; m < 4; ++m)
#pragma unroll
    for (int n = 0; n < 4; ++n) acc[m][n] = z;
  for (int kt = 0; kt < K_DIM / 64; ++kt) {
    const int k0 = kt * 64;
    const int row2 = tid >> 1, ch = (tid & 1) * 32;
    const float* sa = Af + (size_t)(bm * 128 + row2) * K_DIM + k0 + ch;
    const float* sb = Wf + (size_t)(bn * 128 + row2) * K_DIM + k0 + ch;
    unsigned short* da = sA + row2 * 64 + ch;
    unsigned short* db = sB + row2 * 64 + ch;
#pragma unroll
    for (int j = 0; j < 8; ++j) {
      float4 v = *(const float4*)(sa + j * 4);
      ushort4 o; o.x = f2bf(v.x); o.y = f2bf(v.y); o.z = f2bf(v.z); o.w = f2bf(v.w);
      *(ushort4*)(da + j * 4) = o;
      float4 w = *(const float4*)(sb + j * 4);
      ushort4 p; p.x = f2bf(w.x); p.y = f2bf(w.y); p.z = f2bf(w.z); p.w = f2bf(w.w);
      *(ushort4*)(db + j * 4) = p;
    }
    __syncthreads();
#pragma unroll
    for (int ks = 0; ks < 2; ++ks) {
      bf16x8 a4[4], b4[4];
#pragma unroll
      for (int m = 0; m < 4; ++m)
        a4[m] = *(const bf16x8*)(sA + (wr * 64 + m * 16 + (lane & 15)) * 64 +
                                 ks * 32 + (lane >> 4) * 8);
#pragma unroll
      for (int n = 0; n < 4; ++n)
        b4[n] = *(const bf16x8*)(sB + (wc * 64 + n * 16 + (lane & 15)) * 64 +
                                 ks * 32 + (lane >> 4) * 8);
#pragma unroll
      for (int m = 0; m < 4; ++m)
#pragma unroll
        for (int n = 0; n < 4; ++n)
          acc[m][n] = __builtin_amdgcn_mfma_f32_16x16x32_bf16(a4[m], b4[n],
                                                              acc[m][n], 0, 0, 0);
    }
    __syncthreads();
  }
  const int crow = bm * 128 + wr * 64 + ((lane >> 4) << 2);
  const int ccol = bn * 128 + wc * 64 + (lane & 15);
#pragma unroll
  for (int n = 0; n < 4; ++n) {
    const float bv = bias[ccol + n * 16];
#pragma unroll
    for (int m = 0; m < 4; ++m) {
      const size_t base = (size_t)(crow + m * 16) * N_DIM + (ccol + n * 16);
#pragma unroll
      for (int j = 0; j < 4; ++j) C[base + (size_t)j * N_DIM] = acc[m][n][j] + bv;
    }
  }
}

// ------------------------------ launcher --------------------------------------
extern "C" void kernel_launch(void* const* d_in, const int* in_sizes, int n_in,
                              void* d_out, int out_size, void* d_ws, size_t ws_size,
                              hipStream_t stream) {
  const float* A    = (const float*)d_in[0];   // [8192, 16384] fp32
  const float* Wt   = (const float*)d_in[1];   // [4096, 16384] fp32
  const float* bias = (const float*)d_in[2];   // [4096] fp32
  float* out = (float*)d_out;                  // [8192, 4096] fp32

  const size_t elemsA = (size_t)M_DIM * K_DIM;
  const size_t elemsW = (size_t)N_DIM * K_DIM;
  const size_t need = (elemsA + elemsW) * sizeof(unsigned short);  // 384 MiB

  if (ws_size >= need) {
    unsigned short* wsA = (unsigned short*)d_ws;
    unsigned short* wsW = wsA + elemsA;
    cvt_f32_bf16<<<2048, 256, 0, stream>>>(A, wsA, (long)(elemsA / 4));
    cvt_f32_bf16<<<2048, 256, 0, stream>>>(Wt, wsW, (long)(elemsW / 4));
    const int ngrid = (M_DIM / BM) * (N_DIM / BN);  // 512
    gemm256<<<ngrid, NTHR, 0, stream>>>(wsA, wsW, bias, out);
  } else {
    const int ngrid = (M_DIM / 128) * (N_DIM / 128);
    gemm_fallback<<<ngrid, 256, 0, stream>>>(A, Wt, bias, out);
  }
}

// Round 5
// 1164.724 us; speedup vs baseline: 6.1126x; 6.1126x over previous
//
#include <hip/hip_runtime.h>
#include <stdint.h>
#include <stddef.h>

// Row-parallel linear: C[M][N] = A[M][K] * W[N][K]^T + bias
// M = SEQ*BATCH = 8192, N = D_MODEL = 4096, K = D_FF = 16384
#define M_DIM 8192
#define N_DIM 4096
#define K_DIM 16384

#define BM 256
#define BN 256
#define BK 64
#define NTHR 512                  // 8 waves: 2 (M) x 4 (N)
#define K_TILES (K_DIM / BK)      // 256

typedef __attribute__((ext_vector_type(8))) short bf16x8;   // 8 bf16 = 4 VGPRs
typedef __attribute__((ext_vector_type(4))) float f32x4;    // MFMA C/D

#define AS1 __attribute__((address_space(1)))
#define AS3 __attribute__((address_space(3)))

__device__ __forceinline__ unsigned short f2bf(float f) {
  union { float f; unsigned u; } x; x.f = f;
  unsigned r = x.u + 0x7fffu + ((x.u >> 16) & 1u);
  return (unsigned short)(r >> 16);
}

// ---------------- pass 1: fp32 -> bf16 conversion (memory-bound) --------------
__global__ void cvt_f32_bf16(const float* __restrict__ in,
                             unsigned short* __restrict__ out, long n4) {
  long idx = (long)blockIdx.x * blockDim.x + threadIdx.x;
  long stride = (long)gridDim.x * blockDim.x;
  const float4* in4 = (const float4*)in;
  ushort4* out4 = (ushort4*)out;
  for (long i = idx; i < n4; i += stride) {
    float4 v = in4[i];
    ushort4 o;
    o.x = f2bf(v.x); o.y = f2bf(v.y); o.z = f2bf(v.z); o.w = f2bf(v.w);
    out4[i] = o;
  }
}

// ---------------- pass 2: 256x256 bf16 GEMM, m201-style 8-phase ---------------
// 8 phases = 2 K-tiles (even tile -> buf0, odd -> buf1). One half-tile
// (2 global_load_lds per thread) staged per phase; counted vmcnt(4) ONLY at
// phases 4 and 8. Liveness: B-halves of a tile die after its ph2 reads,
// A-halves after ph3 -> staging order A0(v),A1(v),B0(u+2),B1(u+2),A0(u+2),
// A1(u+2),B0(v+2),B1(v+2) never overwrites live data (stage issue is always
// after the barrier that follows the slot's last ds_read). FIFO: vmcnt(4)@ph4
// completes A1(v) (tile v resident for ph5); vmcnt(4)@ph8 completes A1(u+2).
#define BAR()    __builtin_amdgcn_s_barrier()
#define SCHED0() __builtin_amdgcn_sched_barrier(0)
#define WAIT_LGKM0() do { asm volatile("s_waitcnt lgkmcnt(0)" ::: "memory"); \
                          __builtin_amdgcn_sched_barrier(0); } while (0)
#define VMCNT(N) asm volatile("s_waitcnt vmcnt(" #N ")" ::: "memory")

#define MFMA_QUAD(MQ, NP)                                                      \
  do {                                                                         \
    __builtin_amdgcn_s_setprio(1);                                             \
    _Pragma("unroll") for (int mi = 0; mi < 4; ++mi)                           \
      _Pragma("unroll") for (int nn = 0; nn < 2; ++nn)                         \
        _Pragma("unroll") for (int ks = 0; ks < 2; ++ks)                       \
          acc[(MQ)*4 + mi][(NP)*2 + nn] =                                      \
              __builtin_amdgcn_mfma_f32_16x16x32_bf16(                         \
                  af[mi][ks], bf[(NP)*2 + nn][ks],                             \
                  acc[(MQ)*4 + mi][(NP)*2 + nn], 0, 0, 0);                     \
    __builtin_amdgcn_s_setprio(0);                                             \
  } while (0)

__global__ __launch_bounds__(NTHR, 2)
void gemm256(const unsigned short* __restrict__ A,
             const unsigned short* __restrict__ W,
             const float* __restrict__ bias, float* __restrict__ C) {
  __shared__ unsigned short smA[2][BM * BK];   // 2 x 32 KiB
  __shared__ unsigned short smB[2][BN * BK];   // 2 x 32 KiB

  const int tid  = threadIdx.x;
  const int wave = tid >> 6;
  const int lane = tid & 63;
  const int wr = wave >> 2;          // 0..1  (M waves, 128 rows each)
  const int wc = wave & 3;           // 0..3  (N waves, 64 cols each)
  const int g  = lane >> 4;          // frag k-group
  const int xr = (lane & 7) << 4;    // read-side swizzle term

  int csw[2];
  csw[0] = (g * 16) ^ xr;
  csw[1] = (64 + g * 16) ^ xr;

  // XCD-aware bijective swizzle; nwg = 512 (divisible by 8)
  const int nbn = N_DIM / BN;                  // 16
  const int nwg = (M_DIM / BM) * nbn;          // 512
  const int bid = blockIdx.x;
  const int swz = (bid & 7) * (nwg >> 3) + (bid >> 3);
  const int bm = swz / nbn, bn = swz % nbn;
  const int bmBase = bm * BM, bnBase = bn * BN;

  // per-lane pre-swizzled global source offset (elements):
  // lane l -> dest row +(l>>3), 16B slot l&7 holds global slot (l&7)^((l>>3)&7)
  const size_t laneOff = (size_t)(lane >> 3) * K_DIM +
                         (size_t)(((lane & 7) ^ ((lane >> 3) & 7)) * 8);

  const unsigned short* aStage = A + (size_t)bmBase * K_DIM + laneOff;
  const unsigned short* bStage = W + (size_t)bnBase * K_DIM + laneOff;

  f32x4 acc[8][4];
  const f32x4 z = {0.f, 0.f, 0.f, 0.f};
#pragma unroll
  for (int m = 0; m < 8; ++m)
#pragma unroll
    for (int n = 0; n < 4; ++n) acc[m][n] = z;

  bf16x8 af[4][2];   // current m-quad fragments
  bf16x8 bf[4][2];   // all 4 n fragments

  // stage one half-tile (16 KiB = 8 waves x 2 instr x 64 lanes x 16 B)
  auto stageHalfA = [&](int h, int buf, size_t kOff) {
#pragma unroll
    for (int j = 0; j < 2; ++j) {
      const int row0 = h * 128 + wave * 16 + j * 8;     // wave-uniform base row
      const unsigned short* src = aStage + (size_t)row0 * K_DIM + kOff;
      unsigned short* dst = &smA[buf][row0 * BK];
      __builtin_amdgcn_global_load_lds((AS1 void*)src, (AS3 void*)dst, 16, 0, 0);
    }
  };
  auto stageHalfB = [&](int h, int buf, size_t kOff) {
#pragma unroll
    for (int j = 0; j < 2; ++j) {
      const int row0 = h * 128 + wave * 16 + j * 8;
      const unsigned short* src = bStage + (size_t)row0 * K_DIM + kOff;
      unsigned short* dst = &smB[buf][row0 * BK];
      __builtin_amdgcn_global_load_lds((AS1 void*)src, (AS3 void*)dst, 16, 0, 0);
    }
  };

  const char* aRd[2] = {
      (const char*)&smA[0][0] + (wr * 128 + (lane & 15)) * 128,
      (const char*)&smA[1][0] + (wr * 128 + (lane & 15)) * 128};
  const char* bRd[2] = {
      (const char*)&smB[0][0] + (wc * 64 + (lane & 15)) * 128,
      (const char*)&smB[1][0] + (wc * 64 + (lane & 15)) * 128};

  auto readA = [&](const char* p, int mq) {
#pragma unroll
    for (int mi = 0; mi < 4; ++mi)
#pragma unroll
      for (int ks = 0; ks < 2; ++ks)
        af[mi][ks] = *(const bf16x8*)(p + (mq * 64 + mi * 16) * 128 + csw[ks]);
  };
  auto readB = [&](const char* p, int np) {
#pragma unroll
    for (int nn = 0; nn < 2; ++nn)
#pragma unroll
      for (int ks = 0; ks < 2; ++ks)
        bf[np * 2 + nn][ks] =
            *(const bf16x8*)(p + (np * 32 + nn * 16) * 128 + csw[ks]);
  };

  // one iteration = 2 K-tiles: u (buf0), v=u+1 (buf1). `full`=false: final iter.
  auto iter_body = [&](size_t ku, bool full) {
    const size_t kv = ku + BK, ku2 = ku + 2 * BK, kv2 = ku + 3 * BK;

    // ph1: quad(0,0) of u; stage A0(v)
    readA(aRd[0], 0); readB(bRd[0], 0);            // 12 ds_reads
    stageHalfA(0, 1, kv);
    asm volatile("s_waitcnt lgkmcnt(8)" ::: "memory");
    BAR(); WAIT_LGKM0();
    MFMA_QUAD(0, 0);
    BAR(); SCHED0();

    // ph2: quad(0,1) of u; stage A1(v)
    readB(bRd[0], 1);                              // 4 ds_reads
    stageHalfA(1, 1, kv);
    BAR(); WAIT_LGKM0();
    MFMA_QUAD(0, 1);
    BAR(); SCHED0();

    // ph3: quad(1,1) of u; stage B0(u+2)  [B-halves of u died after ph2]
    readA(aRd[0], 1);                              // 8 ds_reads
    if (full) stageHalfB(0, 0, ku2);
    BAR(); WAIT_LGKM0();
    MFMA_QUAD(1, 1);
    BAR(); SCHED0();

    // ph4: quad(1,0) of u; stage B1(u+2); WAIT -> tile v resident for ph5
    if (full) {
      stageHalfB(1, 0, ku2);
      VMCNT(4);
    } else {
      VMCNT(0);
    }
    BAR(); SCHED0();
    MFMA_QUAD(1, 0);
    BAR(); SCHED0();

    // ph5: quad(0,0) of v; stage A0(u+2)  [A-halves of u died after ph3]
    readA(aRd[1], 0); readB(bRd[1], 0);
    if (full) stageHalfA(0, 0, ku2);
    asm volatile("s_waitcnt lgkmcnt(8)" ::: "memory");
    BAR(); WAIT_LGKM0();
    MFMA_QUAD(0, 0);
    BAR(); SCHED0();

    // ph6: quad(0,1) of v; stage A1(u+2)
    readB(bRd[1], 1);
    if (full) stageHalfA(1, 0, ku2);
    BAR(); WAIT_LGKM0();
    MFMA_QUAD(0, 1);
    BAR(); SCHED0();

    // ph7: quad(1,1) of v; stage B0(v+2)  [B-halves of v died after ph6]
    readA(aRd[1], 1);
    if (full) stageHalfB(0, 1, kv2);
    BAR(); WAIT_LGKM0();
    MFMA_QUAD(1, 1);
    BAR(); SCHED0();

    // ph8: quad(1,0) of v; stage B1(v+2); WAIT -> tile u+2 resident for next ph1
    if (full) {
      stageHalfB(1, 1, kv2);
      VMCNT(4);
      BAR(); SCHED0();
    }
    MFMA_QUAD(1, 0);
    if (full) { BAR(); SCHED0(); }
  };

  // ---- prologue: B0(0),B1(0),A0(0),A1(0),B0(1),B1(1); wait tile0 resident ----
  stageHalfB(0, 0, 0); stageHalfB(1, 0, 0);
  stageHalfA(0, 0, 0); stageHalfA(1, 0, 0);
  stageHalfB(0, 1, BK); stageHalfB(1, 1, BK);
  VMCNT(4);                         // completes A1(0); B(1) halves in flight
  BAR(); SCHED0();

  size_t ku = 0;
  for (int J = 0; J < K_TILES / 2 - 1; ++J) {   // 127 steady iterations
    iter_body(ku, true);
    ku += 2 * BK;
  }
  iter_body(ku, false);                          // tiles 254,255: drain

  // ---- epilogue: C = acc + bias. C/D layout: col=lane&15, row=(lane>>4)*4+j
  const int crow0 = bmBase + wr * 128 + ((lane >> 4) << 2);
  const int ccol0 = bnBase + wc * 64 + (lane & 15);
#pragma unroll
  for (int n = 0; n < 4; ++n) {
    const float bv = bias[ccol0 + n * 16];
#pragma unroll
    for (int mi = 0; mi < 8; ++mi) {
      const size_t base = (size_t)(crow0 + mi * 16) * N_DIM + (ccol0 + n * 16);
#pragma unroll
      for (int j = 0; j < 4; ++j)
        C[base + (size_t)j * N_DIM] = acc[mi][n][j] + bv;
    }
  }
}

// ---------------- fallback: fused-cvt 128x128 GEMM (ws too small) -------------
__global__ __launch_bounds__(256)
void gemm_fallback(const float* __restrict__ Af, const float* __restrict__ Wf,
                   const float* __restrict__ bias, float* __restrict__ C) {
  __shared__ __align__(16) unsigned short sA[128 * 64];
  __shared__ __align__(16) unsigned short sB[128 * 64];
  const int tid = threadIdx.x, wave = tid >> 6, lane = tid & 63;
  const int wr = wave >> 1, wc = wave & 1;
  const int nbn = N_DIM / 128, nwg = (M_DIM / 128) * nbn;
  const int swz = (blockIdx.x & 7) * (nwg >> 3) + (blockIdx.x >> 3);
  const int bm = swz / nbn, bn = swz % nbn;
  f32x4 acc[4][4];
  const f32x4 z = {0.f, 0.f, 0.f, 0.f};
#pragma unroll
  for (int m = 0; m < 4; ++m)
#pragma unroll
    for (int n = 0; n < 4; ++n) acc[m][n] = z;
  for (int kt = 0; kt < K_DIM / 64; ++kt) {
    const int k0 = kt * 64;
    const int row2 = tid >> 1, ch = (tid & 1) * 32;
    const float* sa = Af + (size_t)(bm * 128 + row2) * K_DIM + k0 + ch;
    const float* sb = Wf + (size_t)(bn * 128 + row2) * K_DIM + k0 + ch;
    unsigned short* da = sA + row2 * 64 + ch;
    unsigned short* db = sB + row2 * 64 + ch;
#pragma unroll
    for (int j = 0; j < 8; ++j) {
      float4 v = *(const float4*)(sa + j * 4);
      ushort4 o; o.x = f2bf(v.x); o.y = f2bf(v.y); o.z = f2bf(v.z); o.w = f2bf(v.w);
      *(ushort4*)(da + j * 4) = o;
      float4 w = *(const float4*)(sb + j * 4);
      ushort4 p; p.x = f2bf(w.x); p.y = f2bf(w.y); p.z = f2bf(w.z); p.w = f2bf(w.w);
      *(ushort4*)(db + j * 4) = p;
    }
    __syncthreads();
#pragma unroll
    for (int ks = 0; ks < 2; ++ks) {
      bf16x8 a4[4], b4[4];
#pragma unroll
      for (int m = 0; m < 4; ++m)
        a4[m] = *(const bf16x8*)(sA + (wr * 64 + m * 16 + (lane & 15)) * 64 +
                                 ks * 32 + (lane >> 4) * 8);
#pragma unroll
      for (int n = 0; n < 4; ++n)
        b4[n] = *(const bf16x8*)(sB + (wc * 64 + n * 16 + (lane & 15)) * 64 +
                                 ks * 32 + (lane >> 4) * 8);
#pragma unroll
      for (int m = 0; m < 4; ++m)
#pragma unroll
        for (int n = 0; n < 4; ++n)
          acc[m][n] = __builtin_amdgcn_mfma_f32_16x16x32_bf16(a4[m], b4[n],
                                                              acc[m][n], 0, 0, 0);
    }
    __syncthreads();
  }
  const int crow = bm * 128 + wr * 64 + ((lane >> 4) << 2);
  const int ccol = bn * 128 + wc * 64 + (lane & 15);
#pragma unroll
  for (int n = 0; n < 4; ++n) {
    const float bv = bias[ccol + n * 16];
#pragma unroll
    for (int m = 0; m < 4; ++m) {
      const size_t base = (size_t)(crow + m * 16) * N_DIM + (ccol + n * 16);
#pragma unroll
      for (int j = 0; j < 4; ++j) C[base + (size_t)j * N_DIM] = acc[m][n][j] + bv;
    }
  }
}

// ------------------------------ launcher --------------------------------------
extern "C" void kernel_launch(void* const* d_in, const int* in_sizes, int n_in,
                              void* d_out, int out_size, void* d_ws, size_t ws_size,
                              hipStream_t stream) {
  const float* A    = (const float*)d_in[0];   // [8192, 16384] fp32
  const float* Wt   = (const float*)d_in[1];   // [4096, 16384] fp32
  const float* bias = (const float*)d_in[2];   // [4096] fp32
  float* out = (float*)d_out;                  // [8192, 4096] fp32

  const size_t elemsA = (size_t)M_DIM * K_DIM;
  const size_t elemsW = (size_t)N_DIM * K_DIM;
  const size_t need = (elemsA + elemsW) * sizeof(unsigned short);  // 384 MiB

  if (ws_size >= need) {
    unsigned short* wsA = (unsigned short*)d_ws;
    unsigned short* wsW = wsA + elemsA;
    cvt_f32_bf16<<<2048, 256, 0, stream>>>(A, wsA, (long)(elemsA / 4));
    cvt_f32_bf16<<<2048, 256, 0, stream>>>(Wt, wsW, (long)(elemsW / 4));
    const int ngrid = (M_DIM / BM) * (N_DIM / BN);  // 512
    gemm256<<<ngrid, NTHR, 0, stream>>>(wsA, wsW, bias, out);
  } else {
    const int ngrid = (M_DIM / 128) * (N_DIM / 128);
    gemm_fallback<<<ngrid, 256, 0, stream>>>(A, Wt, bias, out);
  }
}

// Round 6
// 1126.287 us; speedup vs baseline: 6.3212x; 1.0341x over previous
//
#include <hip/hip_runtime.h>
#include <stdint.h>
#include <stddef.h>

// Row-parallel linear: C[M][N] = A[M][K] * W[N][K]^T + bias
// M = SEQ*BATCH = 8192, N = D_MODEL = 4096, K = D_FF = 16384
#define M_DIM 8192
#define N_DIM 4096
#define K_DIM 16384

#define BM 256
#define BN 256
#define BK 64
#define NTHR 512                  // 8 waves: 2 (M) x 4 (N)
#define K_TILES (K_DIM / BK)      // 256

typedef __attribute__((ext_vector_type(8))) short bf16x8;   // 8 bf16 = 4 VGPRs
typedef __attribute__((ext_vector_type(4))) float f32x4;    // MFMA C/D

#define AS1 __attribute__((address_space(1)))
#define AS3 __attribute__((address_space(3)))

__device__ __forceinline__ unsigned short f2bf(float f) {
  union { float f; unsigned u; } x; x.f = f;
  unsigned r = x.u + 0x7fffu + ((x.u >> 16) & 1u);
  return (unsigned short)(r >> 16);
}

// ---------------- pass 1: fp32 -> bf16 conversion (memory-bound) --------------
__global__ void cvt_f32_bf16(const float* __restrict__ in,
                             unsigned short* __restrict__ out, long n4) {
  long idx = (long)blockIdx.x * blockDim.x + threadIdx.x;
  long stride = (long)gridDim.x * blockDim.x;
  const float4* in4 = (const float4*)in;
  ushort4* out4 = (ushort4*)out;
  for (long i = idx; i < n4; i += stride) {
    float4 v = in4[i];
    ushort4 o;
    o.x = f2bf(v.x); o.y = f2bf(v.y); o.z = f2bf(v.z); o.w = f2bf(v.w);
    out4[i] = o;
  }
}

// ---------------- pass 2: 256x256 bf16 GEMM, 8-phase, ONE barrier/phase -------
// 8 phases = 2 K-tiles (even->buf0, odd->buf1). One half-tile staged per phase;
// counted vmcnt(4) only at ph4/ph8 (RAW gate: completes all of the tile read
// next). ONE barrier per phase: WAR safety holds because (a) s_barrier bounds
// wave skew to one phase body, (b) every stage targets a slot whose last
// ds_read was >=2 bodies earlier and was drained by that wave's lgkmcnt(0) one
// body after issue (verified slot-by-slot). Read placement (no extra VGPRs,
// every read lands in a dead slot):
//   ph1/ph5: head af0+bf01 (12) -> own lgkm0
//   ph2/ph6: tail af1 (8, SCHED0-fenced after MFMA) -> next phase's lgkm0
//   ph3/ph7: none
//   ph4/ph8: ahead bf23(next tile) (4, after vmcnt+BAR) -> next lgkm0
#define BAR()    __builtin_amdgcn_s_barrier()
#define SCHED0() __builtin_amdgcn_sched_barrier(0)
#define WAIT_LGKM0() do { asm volatile("s_waitcnt lgkmcnt(0)" ::: "memory"); \
                          __builtin_amdgcn_sched_barrier(0); } while (0)
#define VMCNT(N) asm volatile("s_waitcnt vmcnt(" #N ")" ::: "memory")

#define MFMA_QUAD(MQ, NP)                                                      \
  do {                                                                         \
    __builtin_amdgcn_s_setprio(1);                                             \
    _Pragma("unroll") for (int mi = 0; mi < 4; ++mi)                           \
      _Pragma("unroll") for (int nn = 0; nn < 2; ++nn)                         \
        _Pragma("unroll") for (int ks = 0; ks < 2; ++ks)                       \
          acc[(MQ)*4 + mi][(NP)*2 + nn] =                                      \
              __builtin_amdgcn_mfma_f32_16x16x32_bf16(                         \
                  af[mi][ks], bf[(NP)*2 + nn][ks],                             \
                  acc[(MQ)*4 + mi][(NP)*2 + nn], 0, 0, 0);                     \
    __builtin_amdgcn_s_setprio(0);                                             \
  } while (0)

__global__ __launch_bounds__(NTHR, 2)
void gemm256(const unsigned short* __restrict__ A,
             const unsigned short* __restrict__ W,
             const float* __restrict__ bias, float* __restrict__ C) {
  __shared__ unsigned short smA[2][BM * BK];   // 2 x 32 KiB
  __shared__ unsigned short smB[2][BN * BK];   // 2 x 32 KiB

  const int tid  = threadIdx.x;
  const int wave = tid >> 6;
  const int lane = tid & 63;
  const int wr = wave >> 2;          // 0..1  (M waves, 128 rows each)
  const int wc = wave & 3;           // 0..3  (N waves, 64 cols each)
  const int g  = lane >> 4;          // frag k-group
  const int xr = (lane & 7) << 4;    // read-side swizzle term

  int csw[2];
  csw[0] = (g * 16) ^ xr;
  csw[1] = (64 + g * 16) ^ xr;

  // XCD-aware bijective swizzle; nwg = 512 (divisible by 8)
  const int nbn = N_DIM / BN;                  // 16
  const int nwg = (M_DIM / BM) * nbn;          // 512
  const int bid = blockIdx.x;
  const int swz = (bid & 7) * (nwg >> 3) + (bid >> 3);
  const int bm = swz / nbn, bn = swz % nbn;
  const int bmBase = bm * BM, bnBase = bn * BN;

  // per-lane pre-swizzled global source offset (elements):
  // lane l -> dest row +(l>>3), 16B slot l&7 holds global slot (l&7)^((l>>3)&7)
  const size_t laneOff = (size_t)(lane >> 3) * K_DIM +
                         (size_t)(((lane & 7) ^ ((lane >> 3) & 7)) * 8);

  const unsigned short* aStage = A + (size_t)bmBase * K_DIM + laneOff;
  const unsigned short* bStage = W + (size_t)bnBase * K_DIM + laneOff;

  f32x4 acc[8][4];
  const f32x4 z = {0.f, 0.f, 0.f, 0.f};
#pragma unroll
  for (int m = 0; m < 8; ++m)
#pragma unroll
    for (int n = 0; n < 4; ++n) acc[m][n] = z;

  bf16x8 af[4][2];   // current m-quad fragments (shared slot for mq0/mq1)
  bf16x8 bf[4][2];   // all 4 n fragments (bf01 = n0:1, bf23 = n2:3)

  // stage one half-tile (16 KiB = 8 waves x 2 instr x 64 lanes x 16 B)
  auto stageHalfA = [&](int h, int buf, size_t kOff) {
#pragma unroll
    for (int j = 0; j < 2; ++j) {
      const int row0 = h * 128 + wave * 16 + j * 8;     // wave-uniform base row
      const unsigned short* src = aStage + (size_t)row0 * K_DIM + kOff;
      unsigned short* dst = &smA[buf][row0 * BK];
      __builtin_amdgcn_global_load_lds((AS1 void*)src, (AS3 void*)dst, 16, 0, 0);
    }
  };
  auto stageHalfB = [&](int h, int buf, size_t kOff) {
#pragma unroll
    for (int j = 0; j < 2; ++j) {
      const int row0 = h * 128 + wave * 16 + j * 8;
      const unsigned short* src = bStage + (size_t)row0 * K_DIM + kOff;
      unsigned short* dst = &smB[buf][row0 * BK];
      __builtin_amdgcn_global_load_lds((AS1 void*)src, (AS3 void*)dst, 16, 0, 0);
    }
  };

  const char* aRd[2] = {
      (const char*)&smA[0][0] + (wr * 128 + (lane & 15)) * 128,
      (const char*)&smA[1][0] + (wr * 128 + (lane & 15)) * 128};
  const char* bRd[2] = {
      (const char*)&smB[0][0] + (wc * 64 + (lane & 15)) * 128,
      (const char*)&smB[1][0] + (wc * 64 + (lane & 15)) * 128};

  auto readA = [&](const char* p, int mq) {
#pragma unroll
    for (int mi = 0; mi < 4; ++mi)
#pragma unroll
      for (int ks = 0; ks < 2; ++ks)
        af[mi][ks] = *(const bf16x8*)(p + (mq * 64 + mi * 16) * 128 + csw[ks]);
  };
  auto readB = [&](const char* p, int np) {
#pragma unroll
    for (int nn = 0; nn < 2; ++nn)
#pragma unroll
      for (int ks = 0; ks < 2; ++ks)
        bf[np * 2 + nn][ks] =
            *(const bf16x8*)(p + (np * 32 + nn * 16) * 128 + csw[ks]);
  };

  // one iteration = 2 K-tiles: u (buf0), v=u+1 (buf1). full=false: final iter.
  auto iter_body = [&](size_t ku, bool full) {
    const size_t kv = ku + BK, ku2 = ku + 2 * BK, kv2 = ku + 3 * BK;

    // ph1: head af0(u)+bf01(u); stage A0(v) | MFMA(u;0,0)
    readA(aRd[0], 0); readB(bRd[0], 0);            // 12 ds_reads
    stageHalfA(0, 1, kv);
    BAR(); WAIT_LGKM0();
    MFMA_QUAD(0, 0);

    // ph2: stage A1(v) | MFMA(u;0,1) [af0,bf23 pre-drained]; tail af1(u)
    stageHalfA(1, 1, kv);
    BAR(); SCHED0();
    MFMA_QUAD(0, 1);
    SCHED0();
    readA(aRd[0], 1);                              // 8 ds_reads (tail)

    // ph3: stage B0(u+2) | MFMA(u;1,1) [af1 drained here, bf23 held]
    if (full) stageHalfB(0, 0, ku2);
    BAR(); WAIT_LGKM0();
    MFMA_QUAD(1, 1);

    // ph4: stage B1(u+2); vmcnt(4) -> tile v resident | ahead bf23(v); MFMA(u;1,0)
    if (full) {
      stageHalfB(1, 0, ku2);
      VMCNT(4);
    } else {
      VMCNT(0);
    }
    BAR(); SCHED0();
    readB(bRd[1], 1);                              // 4 ds_reads (ahead, dead slot)
    MFMA_QUAD(1, 0);

    // ph5: head af0(v)+bf01(v); stage A0(u+2) | MFMA(v;0,0)
    readA(aRd[1], 0); readB(bRd[1], 0);
    if (full) stageHalfA(0, 0, ku2);
    BAR(); WAIT_LGKM0();
    MFMA_QUAD(0, 0);

    // ph6: stage A1(u+2) | MFMA(v;0,1); tail af1(v)
    if (full) stageHalfA(1, 0, ku2);
    BAR(); SCHED0();
    MFMA_QUAD(0, 1);
    SCHED0();
    readA(aRd[1], 1);

    // ph7: stage B0(v+2) | MFMA(v;1,1)
    if (full) stageHalfB(0, 1, kv2);
    BAR(); WAIT_LGKM0();
    MFMA_QUAD(1, 1);

    // ph8: stage B1(v+2); vmcnt(4) -> tile u+2 resident | ahead bf23(u+2); MFMA(v;1,0)
    if (full) {
      stageHalfB(1, 1, kv2);
      VMCNT(4);
    }
    BAR(); SCHED0();
    if (full) readB(bRd[0], 1);                    // bf23(u+2) for next ph2
    MFMA_QUAD(1, 0);
  };

  // ---- prologue: 6 half-tiles; vmcnt(4) leaves B(1) in flight (steady entry) ----
  stageHalfB(0, 0, 0); stageHalfB(1, 0, 0);
  stageHalfA(0, 0, 0); stageHalfA(1, 0, 0);
  stageHalfB(0, 1, BK); stageHalfB(1, 1, BK);
  VMCNT(4);                         // tile0 fully resident
  BAR(); SCHED0();
  readB(bRd[0], 1);                 // bf23(tile0): the "ph8-prev" ahead-read

  size_t ku = 0;
  for (int J = 0; J < K_TILES / 2 - 1; ++J) {   // 127 steady iterations
    iter_body(ku, true);
    ku += 2 * BK;
  }
  iter_body(ku, false);                          // tiles 254,255: drain

  // ---- epilogue: C = acc + bias. C/D layout: col=lane&15, row=(lane>>4)*4+j
  const int crow0 = bmBase + wr * 128 + ((lane >> 4) << 2);
  const int ccol0 = bnBase + wc * 64 + (lane & 15);
#pragma unroll
  for (int n = 0; n < 4; ++n) {
    const float bv = bias[ccol0 + n * 16];
#pragma unroll
    for (int mi = 0; mi < 8; ++mi) {
      const size_t base = (size_t)(crow0 + mi * 16) * N_DIM + (ccol0 + n * 16);
#pragma unroll
      for (int j = 0; j < 4; ++j)
        C[base + (size_t)j * N_DIM] = acc[mi][n][j] + bv;
    }
  }
}

// ---------------- fallback: fused-cvt 128x128 GEMM (ws too small) -------------
__global__ __launch_bounds__(256)
void gemm_fallback(const float* __restrict__ Af, const float* __restrict__ Wf,
                   const float* __restrict__ bias, float* __restrict__ C) {
  __shared__ __align__(16) unsigned short sA[128 * 64];
  __shared__ __align__(16) unsigned short sB[128 * 64];
  const int tid = threadIdx.x, wave = tid >> 6, lane = tid & 63;
  const int wr = wave >> 1, wc = wave & 1;
  const int nbn = N_DIM / 128, nwg = (M_DIM / 128) * nbn;
  const int swz = (blockIdx.x & 7) * (nwg >> 3) + (blockIdx.x >> 3);
  const int bm = swz / nbn, bn = swz % nbn;
  f32x4 acc[4][4];
  const f32x4 z = {0.f, 0.f, 0.f, 0.f};
#pragma unroll
  for (int m = 0; m < 4; ++m)
#pragma unroll
    for (int n = 0; n < 4; ++n) acc[m][n] = z;
  for (int kt = 0; kt < K_DIM / 64; ++kt) {
    const int k0 = kt * 64;
    const int row2 = tid >> 1, ch = (tid & 1) * 32;
    const float* sa = Af + (size_t)(bm * 128 + row2) * K_DIM + k0 + ch;
    const float* sb = Wf + (size_t)(bn * 128 + row2) * K_DIM + k0 + ch;
    unsigned short* da = sA + row2 * 64 + ch;
    unsigned short* db = sB + row2 * 64 + ch;
#pragma unroll
    for (int j = 0; j < 8; ++j) {
      float4 v = *(const float4*)(sa + j * 4);
      ushort4 o; o.x = f2bf(v.x); o.y = f2bf(v.y); o.z = f2bf(v.z); o.w = f2bf(v.w);
      *(ushort4*)(da + j * 4) = o;
      float4 w = *(const float4*)(sb + j * 4);
      ushort4 p; p.x = f2bf(w.x); p.y = f2bf(w.y); p.z = f2bf(w.z); p.w = f2bf(w.w);
      *(ushort4*)(db + j * 4) = p;
    }
    __syncthreads();
#pragma unroll
    for (int ks = 0; ks < 2; ++ks) {
      bf16x8 a4[4], b4[4];
#pragma unroll
      for (int m = 0; m < 4; ++m)
        a4[m] = *(const bf16x8*)(sA + (wr * 64 + m * 16 + (lane & 15)) * 64 +
                                 ks * 32 + (lane >> 4) * 8);
#pragma unroll
      for (int n = 0; n < 4; ++n)
        b4[n] = *(const bf16x8*)(sB + (wc * 64 + n * 16 + (lane & 15)) * 64 +
                                 ks * 32 + (lane >> 4) * 8);
#pragma unroll
      for (int m = 0; m < 4; ++m)
#pragma unroll
        for (int n = 0; n < 4; ++n)
          acc[m][n] = __builtin_amdgcn_mfma_f32_16x16x32_bf16(a4[m], b4[n],
                                                              acc[m][n], 0, 0, 0);
    }
    __syncthreads();
  }
  const int crow = bm * 128 + wr * 64 + ((lane >> 4) << 2);
  const int ccol = bn * 128 + wc * 64 + (lane & 15);
#pragma unroll
  for (int n = 0; n < 4; ++n) {
    const float bv = bias[ccol + n * 16];
#pragma unroll
    for (int m = 0; m < 4; ++m) {
      const size_t base = (size_t)(crow + m * 16) * N_DIM + (ccol + n * 16);
#pragma unroll
      for (int j = 0; j < 4; ++j) C[base + (size_t)j * N_DIM] = acc[m][n][j] + bv;
    }
  }
}

// ------------------------------ launcher --------------------------------------
extern "C" void kernel_launch(void* const* d_in, const int* in_sizes, int n_in,
                              void* d_out, int out_size, void* d_ws, size_t ws_size,
                              hipStream_t stream) {
  const float* A    = (const float*)d_in[0];   // [8192, 16384] fp32
  const float* Wt   = (const float*)d_in[1];   // [4096, 16384] fp32
  const float* bias = (const float*)d_in[2];   // [4096] fp32
  float* out = (float*)d_out;                  // [8192, 4096] fp32

  const size_t elemsA = (size_t)M_DIM * K_DIM;
  const size_t elemsW = (size_t)N_DIM * K_DIM;
  const size_t need = (elemsA + elemsW) * sizeof(unsigned short);  // 384 MiB

  if (ws_size >= need) {
    unsigned short* wsA = (unsigned short*)d_ws;
    unsigned short* wsW = wsA + elemsA;
    cvt_f32_bf16<<<2048, 256, 0, stream>>>(A, wsA, (long)(elemsA / 4));
    cvt_f32_bf16<<<2048, 256, 0, stream>>>(Wt, wsW, (long)(elemsW / 4));
    const int ngrid = (M_DIM / BM) * (N_DIM / BN);  // 512
    gemm256<<<ngrid, NTHR, 0, stream>>>(wsA, wsW, bias, out);
  } else {
    const int ngrid = (M_DIM / 128) * (N_DIM / 128);
    gemm_fallback<<<ngrid, 256, 0, stream>>>(A, Wt, bias, out);
  }
}